// Round 12
// baseline (926.771 us; speedup 1.0000x reference)
//
#include <hip/hip_runtime.h>

// DenseCRF-RNN fwd, D=64,H=128,W=128, L=2, 5 iters — SINGLE kernel + memset.
// q1 = sigmoid(cur1-cur0); delta = P - Ac*blur3d(q) - M*num(q);
// num = sum_27 w255_o(x)*q(x+d_o)  (u8 weights, kept in REGISTERS w27[27]
// across all 5 iterations — no W array, no W traffic at all). P/M in regs too.
// Grid-wide sync: manual sense-reversal barrier (device-scope atomics +
// __threadfence), valid because the full 1024-block grid is co-resident:
// __launch_bounds__(256,4) caps VGPR at 128 (4 waves/SIMD) and LDS=26.9KB
// -> 4 blocks/CU on 256 CUs = 1024. Bounded spin turns residency failure
// into a visible absmax error instead of a hang.
// ws: bar(64B) | qA | qB (f32, NN+264 apart).

#define DD 64
#define HH 128
#define WW 128
#define NN (DD*HH*WW)   // 1048576
#define PAD 264
#define NBLK 1024

__device__ __forceinline__ float bfac(int p, int dim) {
    const float K[5] = {0.05448868f, 0.24420134f, 0.40261995f, 0.24420134f, 0.05448868f};
    float s = 0.f;
#pragma unroll
    for (int o = -2; o <= 2; ++o) {
        int pp = p + o;
        s += (pp >= 0 && pp < dim) ? K[o + 2] : 0.f;
    }
    return s;
}

__device__ __forceinline__ void ldrow(const float* p, float* r) {
    float4 a = *(const float4*)p;
    float4 b = *(const float4*)(p + 4);
    r[0] = a.x; r[1] = a.y; r[2] = a.z; r[3] = a.w;
    r[4] = b.x; r[5] = b.y; r[6] = b.z; r[7] = b.w;
}

// grid-wide barrier: bar[0]=arrive count, bar[1]=generation
__device__ __forceinline__ void gridbar(unsigned* bar, int tid) {
    __syncthreads();
    if (tid == 0) {
        __threadfence();                         // release: block's writes visible
        unsigned gen = atomicAdd(&bar[1], 0u);   // read generation BEFORE arriving
        __threadfence();
        unsigned ticket = atomicAdd(&bar[0], 1u);
        if (ticket == NBLK - 1u) {
            atomicExch(&bar[0], 0u);             // reset for next use
            __threadfence();
            atomicAdd(&bar[1], 1u);              // release everyone
        } else {
            int guard = 0;
            while (atomicAdd(&bar[1], 0u) == gen) {
                if (++guard > (1 << 20)) break;  // safety valve (no hang)
                __builtin_amdgcn_s_sleep(8);
            }
        }
        __threadfence();                         // acquire: see remote writes
    }
    __syncthreads();
}

__global__ __launch_bounds__(256, 4) void crf_fused(
    const float* __restrict__ img, const float* __restrict__ h,
    const float* __restrict__ f1, const float* __restrict__ w0,
    const float* __restrict__ sw, const float* __restrict__ bw,
    const float* __restrict__ cm,
    float* __restrict__ qA, float* __restrict__ qB,
    unsigned* __restrict__ bar, float* __restrict__ out)
{
    const float K0 = 0.05448868f, K1 = 0.24420134f, K2 = 0.40261995f;
    const float Sc[4] = {1.f, 0.80073740f, 0.64118039f, 0.51341712f};

    __shared__ float qs[12][12][20];   // q tile, halo 2 (11.5 KB)
    __shared__ float t1[12][12][16];   // blur-x scratch; pre reuses as img tile
    __shared__ float t2[12][8][16];    // blur-xy scratch

    const int tid = threadIdx.x;
    const int x0 = blockIdx.x * 16, y0 = blockIdx.y * 8, z0 = blockIdx.z * 8;
    const int lx = (tid & 3) * 4, ly = (tid >> 2) & 7, lz = tid >> 5;
    const int x = x0 + lx, y = y0 + ly, z = z0 + lz;
    const int g = (z << 14) + (y << 7) + x;

    const float cd0 = cm[2] - cm[0], cd1 = cm[3] - cm[1];
    const float Ksp = cd0 * sw[0] + cd1 * sw[2];
    const float Kbl = cd0 * bw[0] + cd1 * bw[2];
    const float Bc  = cd0 * (bw[1] - bw[0]) + cd1 * (bw[3] - bw[2]);
    const float Ac  = cd0 * (sw[1] - sw[0]) + cd1 * (sw[3] - sw[2]);

    // ---- pre: weights -> REGISTERS (w27), P/M -> registers, q0, f1 copy ----
    unsigned w27[27];
    float pr[4], mv[4];
    {
        float* imsf = &t1[0][0][0];    // img tile 10x10x20 = 2000 f (cap 2304)
        for (int idx = tid; idx < 2000; idx += 256) {
            int lz2 = idx / 200, r = idx - lz2 * 200, ly2 = r / 20, lx2 = r - ly2 * 20;
            int gz = z0 + lz2 - 1, gy = y0 + ly2 - 1, gx = x0 + lx2 - 1;
            float v = 0.f;
            if ((unsigned)gz < 64u && (unsigned)gy < 128u && (unsigned)gx < 128u)
                v = img[(gz << 14) + (gy << 7) + gx];
            imsf[idx] = v;
        }
        __syncthreads();

        float rowC[8];
        ldrow(imsf + ((lz + 1) * 10 + (ly + 1)) * 20 + lx, rowC);
        const float Ic[4] = {rowC[1], rowC[2], rowC[3], rowC[4]};
        float den[4] = {0.f, 0.f, 0.f, 0.f}, numi[4] = {0.f, 0.f, 0.f, 0.f};
        float rI[8];
#pragma unroll
        for (int r9 = 0; r9 < 9; ++r9) {
            const int dz = r9 / 3 - 1, dy = r9 % 3 - 1;
            ldrow(imsf + ((lz + 1 + dz) * 10 + (ly + 1 + dy)) * 20 + lx, rI);
            const bool zyin = ((unsigned)(z + dz) < 64u) && ((unsigned)(y + dy) < 128u);
#pragma unroll
            for (int c = 0; c < 3; ++c) {
                const int dx = c - 1;
                const float s = Sc[dz * dz + dy * dy + dx * dx];
                unsigned pack = 0;
#pragma unroll
                for (int xi = 0; xi < 4; ++xi) {
                    float dd = Ic[xi] - rI[xi + c];
                    float w = s * __expf(-2.f * dd * dd);
                    den[xi] += w;
                    bool inb = zyin && ((unsigned)(x + xi + dx) < 128u);
                    numi[xi] += inb ? w : 0.f;
                    pack |= ((unsigned)(w * 255.f + 0.5f)) << (8 * xi);
                }
                w27[r9 * 3 + c] = pack;
            }
        }
        float4 h0v = *(const float4*)&h[g];
        float4 h1v = *(const float4*)&h[NN + g];
        float4 f1v = *(const float4*)&f1[g];
        float hh0[4] = {h0v.x, h0v.y, h0v.z, h0v.w};
        float hh1[4] = {h1v.x, h1v.y, h1v.z, h1v.w};
        float ff[4]  = {f1v.x, f1v.y, f1v.z, f1v.w};
        const float w00 = w0[0];
        const float bz = bfac(z, 64), by = bfac(y, 128);
        float qv[4];
#pragma unroll
        for (int xi = 0; xi < 4; ++xi) {
            float dq = hh1[xi] - hh0[xi];
            float logp = -0.5f * Ic[xi] * Ic[xi] - 0.91893853320467274f;
            float t = -(w00 + logp - ff[xi]);
            float bones = bz * by * bfac(x + xi, 128);
            qv[xi] = 1.f / (1.f + __expf(-dq));
            pr[xi] = dq * t - Ksp * bones - Kbl * (numi[xi] / den[xi]);
            mv[xi] = Bc / (den[xi] * 255.f);
        }
        *(float4*)&qA[g] = {qv[0], qv[1], qv[2], qv[3]};
        *(float4*)&out[2 * NN + g] = f1v;    // f_1 passthrough
    }

    gridbar(bar, tid);                       // all q0 visible device-wide

    const float* srcq = qA;
    float* dstq = qB;

#pragma unroll 1
    for (int it = 0; it < 5; ++it) {
        // stage q tile (halo 2)
        float* qf = &qs[0][0][0];
        for (int idx = tid; idx < 2880; idx += 256) {
            int lz2 = idx / 240, r = idx - lz2 * 240, ly2 = r / 20, lx2 = r - ly2 * 20;
            int gz = z0 + lz2 - 2, gy = y0 + ly2 - 2, gx = x0 + lx2 - 2;
            float v = 0.f;
            if ((unsigned)gz < 64u && (unsigned)gy < 128u && (unsigned)gx < 128u)
                v = srcq[(gz << 14) + (gy << 7) + gx];
            qf[idx] = v;
        }
        __syncthreads();

        // blur along x
        for (int idx = tid; idx < 576; idx += 256) {
            int lz2 = idx / 48, r = idx - lz2 * 48, ly2 = r / 4, c4 = (r - ly2 * 4) * 4;
            const float* row = &qs[lz2][ly2][c4];
            float4 a = *(const float4*)row;
            float4 b = *(const float4*)(row + 4);
            float4 o;
            o.x = K0 * (a.x + b.x) + K1 * (a.y + a.w) + K2 * a.z;
            o.y = K0 * (a.y + b.y) + K1 * (a.z + b.x) + K2 * a.w;
            o.z = K0 * (a.z + b.z) + K1 * (a.w + b.y) + K2 * b.x;
            o.w = K0 * (a.w + b.w) + K1 * (b.x + b.z) + K2 * b.y;
            *(float4*)&t1[lz2][ly2][c4] = o;
        }
        __syncthreads();

        // blur along y
        for (int idx = tid; idx < 384; idx += 256) {
            int lz2 = idx / 32, r = idx - lz2 * 32, ly2 = r / 4, c4 = (r - ly2 * 4) * 4;
            float4 r0 = *(const float4*)&t1[lz2][ly2][c4];
            float4 r1 = *(const float4*)&t1[lz2][ly2 + 1][c4];
            float4 r2 = *(const float4*)&t1[lz2][ly2 + 2][c4];
            float4 r3 = *(const float4*)&t1[lz2][ly2 + 3][c4];
            float4 r4 = *(const float4*)&t1[lz2][ly2 + 4][c4];
            float4 o;
            o.x = K0 * (r0.x + r4.x) + K1 * (r1.x + r3.x) + K2 * r2.x;
            o.y = K0 * (r0.y + r4.y) + K1 * (r1.y + r3.y) + K2 * r2.y;
            o.z = K0 * (r0.z + r4.z) + K1 * (r1.z + r3.z) + K2 * r2.z;
            o.w = K0 * (r0.w + r4.w) + K1 * (r1.w + r3.w) + K2 * r2.w;
            *(float4*)&t2[lz2][ly2][c4] = o;
        }
        __syncthreads();

        // blur along z
        float4 za = *(const float4*)&t2[lz][ly][lx];
        float4 zb = *(const float4*)&t2[lz + 1][ly][lx];
        float4 zc = *(const float4*)&t2[lz + 2][ly][lx];
        float4 zd = *(const float4*)&t2[lz + 3][ly][lx];
        float4 ze = *(const float4*)&t2[lz + 4][ly][lx];
        float sp[4];
        sp[0] = K0 * (za.x + ze.x) + K1 * (zb.x + zd.x) + K2 * zc.x;
        sp[1] = K0 * (za.y + ze.y) + K1 * (zb.y + zd.y) + K2 * zc.y;
        sp[2] = K0 * (za.z + ze.z) + K1 * (zb.z + zd.z) + K2 * zc.z;
        sp[3] = K0 * (za.w + ze.w) + K1 * (zb.w + zd.w) + K2 * zc.w;

        // bilateral: 27 dirs, u8 weights from registers
        float num[4] = {0.f, 0.f, 0.f, 0.f};
        float qrow[8];
#pragma unroll
        for (int r9 = 0; r9 < 9; ++r9) {
            const int dz = r9 / 3 - 1, dy = r9 % 3 - 1;
            ldrow(&qs[lz + 2 + dz][ly + 2 + dy][lx], qrow);
#pragma unroll
            for (int c = 0; c < 3; ++c) {
                unsigned wv = w27[r9 * 3 + c];
#pragma unroll
                for (int xi = 0; xi < 4; ++xi)
                    num[xi] += (float)((wv >> (8 * xi)) & 0xffu) * qrow[xi + 1 + c];
            }
        }

        float qn[4];
#pragma unroll
        for (int xi = 0; xi < 4; ++xi) {
            float dn = pr[xi] - Ac * sp[xi] - mv[xi] * num[xi];
            qn[xi] = 1.f / (1.f + __expf(-dn));
        }

        if (it < 4) {
            *(float4*)&dstq[g] = {qn[0], qn[1], qn[2], qn[3]};
            const float* tp = srcq; srcq = dstq; dstq = (float*)tp;
            gridbar(bar, tid);
        } else {
            float4 o1 = {qn[0], qn[1], qn[2], qn[3]};
            float4 o0 = {1.f - qn[0], 1.f - qn[1], 1.f - qn[2], 1.f - qn[3]};
            *(float4*)&out[g] = o0;
            *(float4*)&out[NN + g] = o1;
        }
    }
}

extern "C" void kernel_launch(void* const* d_in, const int* in_sizes, int n_in,
                              void* d_out, int out_size, void* d_ws, size_t ws_size,
                              hipStream_t stream)
{
    const float* img = (const float*)d_in[0];
    const float* h   = (const float*)d_in[1];
    const float* f1  = (const float*)d_in[2];
    const float* w0  = (const float*)d_in[3];
    const float* sw  = (const float*)d_in[4];
    const float* bw  = (const float*)d_in[5];
    const float* cm  = (const float*)d_in[6];
    float* out = (float*)d_out;

    unsigned* bar = (unsigned*)d_ws;           // [0]=count, [1]=gen
    float* qA = (float*)d_ws + 64;
    float* qB = qA + (NN + PAD);

    hipMemsetAsync(bar, 0, 64, stream);        // ws is poisoned before each call

    dim3 grid(WW / 16, HH / 8, DD / 8);        // 1024 blocks = 4/CU, co-resident
    crf_fused<<<grid, 256, 0, stream>>>(img, h, f1, w0, sw, bw, cm,
                                        qA, qB, bar, out);
}